// Round 4
// baseline (413.355 us; speedup 1.0000x reference)
//
#include <hip/hip_runtime.h>
#include <hip/hip_bf16.h>

#define NC 10
#define DD 64
#define BB 32
#define SS 16384
#define CHUNK 512
#define NCHUNK (SS / CHUNK)                  // 32
#define NBLK (BB * NCHUNK)                   // 1024
#define NWAVE 16
#define RPW (CHUNK / NWAVE)                  // 32 rows per wave
#define OUT_MAIN (2 * BB * NC * DD)          // 40960
#define WS_WORDS (BB * NC * DD + BB * NC)    // 20800 words = 83,200 B

// -------------------------------------------- kernel 0: zero ws + init out --
__global__ __launch_bounds__(256) void zero_kernel(
    int* __restrict__ ws, int nws, float* __restrict__ out_init)
{
    int i = blockIdx.x * 256 + threadIdx.x;
    if (i < nws) ws[i] = 0;
    if (blockIdx.x == 0 && threadIdx.x < 2 * DD) out_init[threadIdx.x] = 0.f;
}

// ------------------------------------------------- kernel 1: segment sums ---
// 1024 blocks x 1024 threads (16 waves) -> 2 blocks/CU = 32 waves/CU (100%).
// Wave-private LDS tile [10][64] (no cross-wave atomic contention); labels
// pre-staged to LDS (loop's only VMEM dep = x load); 8 x-loads in flight per
// wave. ds_add banks = lane%32 -> 2-way (free, m136).
__global__ __launch_bounds__(1024) void seg_kernel(
    const float* __restrict__ x, const int* __restrict__ labels,
    float* __restrict__ seg, int* __restrict__ cnt)
{
    __shared__ float tiles[NWAVE * NC * DD];   // 40,960 B
    __shared__ int lab_s[CHUNK];               // 2,048 B
    __shared__ int scnt[NC];

    const int tid = threadIdx.x;
    const int blk = blockIdx.x;
    const int b = blk / NCHUNK, chunk = blk % NCHUNK;
    const int s0 = chunk * CHUNK;
    const int w = tid >> 6, lane = tid & 63;

    float* tile = tiles + w * (NC * DD);
    #pragma unroll
    for (int c = 0; c < NC; ++c) tile[c * DD + lane] = 0.f;
    if (tid < CHUNK) lab_s[tid] = labels[b * SS + s0 + tid];
    if (tid >= CHUNK && tid < CHUNK + NC) scnt[tid - CHUNK] = 0;
    __syncthreads();

    if (tid < CHUNK) atomicAdd(&scnt[lab_s[tid]], 1);

    const float* xg = x + ((long)b * SS + s0 + w * RPW) * DD + lane;
    const int* lw = lab_s + w * RPW;

    #pragma unroll
    for (int r0 = 0; r0 < RPW; r0 += 8) {
        int l[8]; float v[8];
        #pragma unroll
        for (int u = 0; u < 8; ++u) l[u] = lw[r0 + u];       // LDS broadcast
        #pragma unroll
        for (int u = 0; u < 8; ++u) v[u] = xg[(r0 + u) * DD]; // 8 x 256B in flight
        #pragma unroll
        for (int u = 0; u < 8; ++u)
            atomicAdd(&tile[l[u] * DD + lane], v[u]);         // ds_add_f32
    }
    __syncthreads();

    // merge 16 wave tiles -> global (native f32 atomic, 640 adds/block)
    if (tid < NC * DD) {
        float s = 0.f;
        #pragma unroll
        for (int wv = 0; wv < NWAVE; ++wv) s += tiles[wv * (NC * DD) + tid];
        unsafeAtomicAdd(&seg[b * (NC * DD) + tid], s);
    }
    if (tid < NC) atomicAdd(&cnt[b * NC + tid], scnt[tid]);
}

// --------------------------------------------------- kernel 2: MLP heads ----
// 320 blocks x 128 threads; wave 0 = mean head, wave 1 = logvar head (runs
// both heads in parallel). Weights staged to LDS (+1 pad). Init sums folded
// in via native f32 global atomics (region zeroed by kernel 0).
__global__ __launch_bounds__(128) void mlp_kernel(
    const float* __restrict__ seg, const int* __restrict__ cnt,
    const float* wm1, const float* bm1, const float* wm2, const float* bm2,
    const float* wm3, const float* bm3,
    const float* wv1, const float* bv1, const float* wv2, const float* bv2,
    const float* wv3, const float* bv3,
    const int* __restrict__ Kptr, float* __restrict__ out)
{
    const int blk = blockIdx.x;                // b*NC + c
    const int head = threadIdx.x >> 6, lane = threadIdx.x & 63;

    __shared__ float w_lds[2][DD * (DD + 1)];  // 33,280 B
    __shared__ float h[2][DD];

    const float slot = seg[blk * DD + lane] / (float)cnt[blk];
    const float* Ws[2][3] = {{wm1, wm2, wm3}, {wv1, wv2, wv3}};
    const float* Bs[2][3] = {{bm1, bm2, bm3}, {bv1, bv2, bv3}};

    h[head][lane] = slot;
    float val = 0.f;
    #pragma unroll
    for (int layer = 0; layer < 3; ++layer) {
        const float* W = Ws[head][layer];
        const float bias = Bs[head][layer][lane];
        #pragma unroll
        for (int i = 0; i < DD; ++i)           // coalesced 256B rows -> LDS
            w_lds[head][i * (DD + 1) + lane] = W[i * DD + lane];
        __syncthreads();
        float z = bias;
        #pragma unroll
        for (int d = 0; d < DD; ++d)           // h[d] broadcast; 2-way banks
            z += h[head][d] * w_lds[head][lane * (DD + 1) + d];
        val = (layer < 2) ? fmaxf(z, 0.f)
                          : (2.f / (1.f + __expf(-z)) - 1.f);
        __syncthreads();
        h[head][lane] = val;
    }
    out[head * (BB * NC * DD) + blk * DD + lane] = val;
    unsafeAtomicAdd(&out[OUT_MAIN + head * DD + lane],
                    val / (float)(BB * Kptr[0]));
}

// ------------------------------------- fallback: fused, zero-ws, 32 blocks --
__global__ __launch_bounds__(1024) void fused_fallback_kernel(
    const float* __restrict__ x, const int* __restrict__ labels,
    const float* wm1, const float* bm1, const float* wm2, const float* bm2,
    const float* wm3, const float* bm3,
    const float* wv1, const float* bv1, const float* wv2, const float* bv2,
    const float* wv3, const float* bv3,
    float* __restrict__ out)
{
    __shared__ float ssum[NC * DD];
    __shared__ int scnt[NC];
    __shared__ float hs[NC][DD];
    __shared__ float w_lds[DD * (DD + 1)];

    const int tid = threadIdx.x;
    const int b = blockIdx.x;
    const int wave = tid >> 6, lane = tid & 63;

    for (int i = tid; i < NC * DD; i += 1024) ssum[i] = 0.f;
    if (tid < NC) scnt[tid] = 0;
    __syncthreads();

    const int* lab = labels + b * SS;
    {
        int c_acc[NC];
        #pragma unroll
        for (int c = 0; c < NC; ++c) c_acc[c] = 0;
        for (int i = 0; i < 16; ++i) {
            int l = lab[wave * 1024 + i * 64 + lane];
            #pragma unroll
            for (int c = 0; c < NC; ++c)
                c_acc[c] += (int)__popcll(__ballot(l == c));
        }
        if (lane == 0) {
            #pragma unroll
            for (int c = 0; c < NC; ++c) atomicAdd(&scnt[c], c_acc[c]);
        }
    }

    const float* xb = x + ((long)b * SS + wave * 1024) * DD + lane;
    const int* labw = lab + wave * 1024;
    for (int r = 0; r < 1024; r += 8) {
        float v[8]; int l[8];
        #pragma unroll
        for (int u = 0; u < 8; ++u) { v[u] = xb[(r + u) * DD]; l[u] = labw[r + u]; }
        #pragma unroll
        for (int u = 0; u < 8; ++u) atomicAdd(&ssum[l[u] * DD + lane], v[u]);
    }
    __syncthreads();

    const int c = tid >> 6;
    const bool act = (tid < NC * DD);
    float slot = 0.f;
    if (act) slot = ssum[c * DD + lane] / (float)scnt[c];

    const float* Ws[2][3] = {{wm1, wm2, wm3}, {wv1, wv2, wv3}};
    const float* Bs[2][3] = {{bm1, bm2, bm3}, {bv1, bv2, bv3}};

    #pragma unroll
    for (int head = 0; head < 2; ++head) {
        if (act) hs[c][lane] = slot;
        float val = 0.f;
        #pragma unroll
        for (int layer = 0; layer < 3; ++layer) {
            const float* W = Ws[head][layer];
            for (int i = tid; i < DD * DD; i += 1024)
                w_lds[(i >> 6) * (DD + 1) + (i & 63)] = W[i];
            __syncthreads();
            if (act) {
                float z = Bs[head][layer][lane];
                #pragma unroll
                for (int d = 0; d < DD; ++d)
                    z += hs[c][d] * w_lds[lane * (DD + 1) + d];
                val = (layer < 2) ? fmaxf(z, 0.f)
                                  : (2.f / (1.f + __expf(-z)) - 1.f);
            }
            __syncthreads();
            if (act) hs[c][lane] = val;
        }
        if (act) out[head * (BB * NC * DD) + (b * NC + c) * DD + lane] = val;
        __syncthreads();
    }
}

__global__ __launch_bounds__(128) void init_fallback_kernel(
    const float* __restrict__ outro, const int* __restrict__ Kptr,
    float* __restrict__ out)
{
    const int t = threadIdx.x;
    const int head = t >> 6, lane = t & 63;
    const float* src = outro + head * (BB * NC * DD) + lane;
    float s = 0.f;
    for (int r = 0; r < BB * NC; ++r) s += src[r * DD];
    out[OUT_MAIN + t] = s / (float)(BB * Kptr[0]);
}

extern "C" void kernel_launch(void* const* d_in, const int* in_sizes, int n_in,
                              void* d_out, int out_size, void* d_ws, size_t ws_size,
                              hipStream_t stream)
{
    const float* x      = (const float*)d_in[0];
    const int*   labels = (const int*)d_in[1];
    const int*   K      = (const int*)d_in[2];
    const float* wm1 = (const float*)d_in[3];
    const float* bm1 = (const float*)d_in[4];
    const float* wm2 = (const float*)d_in[5];
    const float* bm2 = (const float*)d_in[6];
    const float* wm3 = (const float*)d_in[7];
    const float* bm3 = (const float*)d_in[8];
    const float* wv1 = (const float*)d_in[9];
    const float* bv1 = (const float*)d_in[10];
    const float* wv2 = (const float*)d_in[11];
    const float* bv2 = (const float*)d_in[12];
    const float* wv3 = (const float*)d_in[13];
    const float* bv3 = (const float*)d_in[14];
    float* out = (float*)d_out;

    if (ws_size >= (size_t)WS_WORDS * 4) {
        float* seg = (float*)d_ws;
        int*   cnt = (int*)((char*)d_ws + (size_t)BB * NC * DD * 4);
        zero_kernel<<<(WS_WORDS + 255) / 256, 256, 0, stream>>>(
            (int*)d_ws, WS_WORDS, out + OUT_MAIN);
        seg_kernel<<<NBLK, 1024, 0, stream>>>(x, labels, seg, cnt);
        mlp_kernel<<<BB * NC, 128, 0, stream>>>(
            seg, cnt,
            wm1, bm1, wm2, bm2, wm3, bm3,
            wv1, bv1, wv2, bv2, wv3, bv3, K, out);
    } else {
        fused_fallback_kernel<<<BB, 1024, 0, stream>>>(
            x, labels,
            wm1, bm1, wm2, bm2, wm3, bm3,
            wv1, bv1, wv2, bv2, wv3, bv3, out);
        init_fallback_kernel<<<1, 128, 0, stream>>>((const float*)d_out, K, out);
    }
}

// Round 6
// 345.655 us; speedup vs baseline: 1.1959x; 1.1959x over previous
//
#include <hip/hip_runtime.h>
#include <hip/hip_bf16.h>

#define NC 10
#define DD 64
#define BB 32
#define SS 16384
#define CHUNK 256
#define NCHUNK (SS / CHUNK)                  // 64
#define NBLK (BB * NCHUNK)                   // 2048
#define TSTR 65                              // tile row stride (pad)
#define TSZ (NC * TSTR)                      // 650
#define OUT_MAIN (2 * BB * NC * DD)          // 40960
#define WS_WORDS (BB * NC * DD + BB * NC)    // 20800 words = 83,200 B

// -------------------------------------------- kernel 0: zero ws + init out --
__global__ __launch_bounds__(256) void zero_kernel(
    int* __restrict__ ws, int nws, float* __restrict__ out_init)
{
    int i = blockIdx.x * 256 + threadIdx.x;
    if (i < nws) ws[i] = 0;
    if (blockIdx.x == 0 && threadIdx.x < 2 * DD) out_init[threadIdx.x] = 0.f;
}

// ------------------------------------------------- kernel 1: segment sums ---
// 2048 blocks x 256 thr (4 waves) -> 8 blocks/CU, 32 waves/CU.
// dwordx4 loads: one instruction = 1 KB = 4 rows (16 lanes/row, 4 dims/lane);
// 8 instructions (8 KB) in flight per wave. Wave-private LDS tile, stride 65.
__global__ __launch_bounds__(256, 8) void seg_kernel(
    const float4* __restrict__ x4, const int* __restrict__ labels,
    float* __restrict__ seg, int* __restrict__ cnt)
{
    __shared__ float tiles[4][TSZ];            // 10,400 B
    __shared__ int lab_s[CHUNK];
    __shared__ int scnt[NC];

    const int tid = threadIdx.x;
    const int blk = blockIdx.x;
    const int b = blk >> 6, chunk = blk & 63;
    const int s0 = chunk * CHUNK;
    const int w = tid >> 6, lane = tid & 63;
    const int g = lane >> 4, m = lane & 15;    // row-group, dim-quad

    float* tile = tiles[w];
    for (int i = lane; i < TSZ; i += 64) tile[i] = 0.f;
    lab_s[tid] = labels[b * SS + s0 + tid];
    if (tid < NC) scnt[tid] = 0;
    __syncthreads();

    atomicAdd(&scnt[lab_s[tid]], 1);

    // float4 element index of (row, dim-quad m): row*16 + m ; lane = g*16+m
    const float4* xg = x4 + ((long)(b * SS + s0 + w * 64)) * 16 + lane;
    const int* lw = lab_s + w * 64;

    #pragma unroll
    for (int r0 = 0; r0 < 64; r0 += 32) {      // 2 x (8 wave-loads = 32 rows)
        int l[8]; float4 v[8];
        #pragma unroll
        for (int u = 0; u < 8; ++u) l[u] = lw[r0 + u * 4 + g];
        #pragma unroll
        for (int u = 0; u < 8; ++u) v[u] = xg[(r0 + u * 4) * 16];
        #pragma unroll
        for (int u = 0; u < 8; ++u) {
            float* t = &tile[l[u] * TSTR + m * 4];
            atomicAdd(t + 0, v[u].x);          // ds_add_f32 x4
            atomicAdd(t + 1, v[u].y);
            atomicAdd(t + 2, v[u].z);
            atomicAdd(t + 3, v[u].w);
        }
    }
    __syncthreads();

    // merge 4 wave tiles -> global: 640 elements, 256 threads, strided
    for (int i = tid; i < NC * DD; i += 256) {
        const int c = i >> 6, d = i & 63;
        float s = tiles[0][c * TSTR + d] + tiles[1][c * TSTR + d]
                + tiles[2][c * TSTR + d] + tiles[3][c * TSTR + d];
        unsafeAtomicAdd(&seg[b * (NC * DD) + i], s);
    }
    if (tid < NC) atomicAdd(&cnt[b * NC + tid], scnt[tid]);
}

// --------------------------------------------------- kernel 2: MLP heads ----
// 64 blocks (b x head) x 1024 thr. Each layer: every thread stages ONE float4
// of W (one instruction, fully parallel) -> LDS (stride 65); waves 0..9 = the
// 10 cluster rows. Init sums LDS-reduced, one global atomic per block.
__global__ __launch_bounds__(1024) void mlp_kernel(
    const float* __restrict__ seg, const int* __restrict__ cnt,
    const float* wm1, const float* bm1, const float* wm2, const float* bm2,
    const float* wm3, const float* bm3,
    const float* wv1, const float* bv1, const float* wv2, const float* bv2,
    const float* wv3, const float* bv3,
    const int* __restrict__ Kptr, float* __restrict__ out)
{
    const int blk = blockIdx.x;                // b*2 + head
    const int b = blk >> 1, head = blk & 1;
    const int tid = threadIdx.x;
    const int w = tid >> 6, lane = tid & 63;

    __shared__ float w_lds[DD * TSTR];         // 16,640 B
    __shared__ float hs[NC][DD];
    __shared__ float hsum[DD];

    const float* W0 = head ? wv1 : wm1;
    const float* W1 = head ? wv2 : wm2;
    const float* W2 = head ? wv3 : wm3;
    const float* B0 = head ? bv1 : bm1;
    const float* B1 = head ? bv2 : bm2;
    const float* B2 = head ? bv3 : bm3;
    const float* Wl[3] = {W0, W1, W2};
    const float* Bl[3] = {B0, B1, B2};

    if (tid < DD) hsum[tid] = 0.f;
    if (w < NC) hs[w][lane] = seg[(b * NC + w) * DD + lane]
                              / (float)cnt[b * NC + w];
    float val = 0.f;
    const int j = tid >> 4, d0 = (tid & 15) * 4;   // stage target

    #pragma unroll
    for (int layer = 0; layer < 3; ++layer) {
        const float4 wv = ((const float4*)Wl[layer])[tid];  // 1 insn / thread
        const float bias = (w < NC) ? Bl[layer][lane] : 0.f;
        __syncthreads();                       // prev-layer dots done
        w_lds[j * TSTR + d0 + 0] = wv.x;
        w_lds[j * TSTR + d0 + 1] = wv.y;
        w_lds[j * TSTR + d0 + 2] = wv.z;
        w_lds[j * TSTR + d0 + 3] = wv.w;
        __syncthreads();                       // W staged
        if (w < NC) {
            float z = bias;
            #pragma unroll
            for (int d = 0; d < DD; ++d)       // banks (lane+d)%32 -> 2-way
                z += hs[w][d] * w_lds[lane * TSTR + d];
            val = (layer < 2) ? fmaxf(z, 0.f)
                              : (2.f / (1.f + __expf(-z)) - 1.f);
            hs[w][lane] = val;                 // barrier-ordered vs next read
        }
    }
    if (w < NC) {
        out[head * (BB * NC * DD) + (b * NC + w) * DD + lane] = val;
        atomicAdd(&hsum[lane], val);           // 10 waves -> LDS
    }
    __syncthreads();
    if (tid < DD)
        unsafeAtomicAdd(&out[OUT_MAIN + head * DD + tid],
                        hsum[tid] / (float)(BB * Kptr[0]));
}

// ------------------------------------- fallback: fused, zero-ws, 32 blocks --
__global__ __launch_bounds__(1024) void fused_fallback_kernel(
    const float* __restrict__ x, const int* __restrict__ labels,
    const float* wm1, const float* bm1, const float* wm2, const float* bm2,
    const float* wm3, const float* bm3,
    const float* wv1, const float* bv1, const float* wv2, const float* bv2,
    const float* wv3, const float* bv3,
    float* __restrict__ out)
{
    __shared__ float ssum[NC * DD];
    __shared__ int scnt[NC];
    __shared__ float hs[NC][DD];
    __shared__ float w_lds[DD * (DD + 1)];

    const int tid = threadIdx.x;
    const int b = blockIdx.x;
    const int wave = tid >> 6, lane = tid & 63;

    for (int i = tid; i < NC * DD; i += 1024) ssum[i] = 0.f;
    if (tid < NC) scnt[tid] = 0;
    __syncthreads();

    const int* lab = labels + b * SS;
    {
        int c_acc[NC];
        #pragma unroll
        for (int c = 0; c < NC; ++c) c_acc[c] = 0;
        for (int i = 0; i < 16; ++i) {
            int l = lab[wave * 1024 + i * 64 + lane];
            #pragma unroll
            for (int c = 0; c < NC; ++c)
                c_acc[c] += (int)__popcll(__ballot(l == c));
        }
        if (lane == 0) {
            #pragma unroll
            for (int c = 0; c < NC; ++c) atomicAdd(&scnt[c], c_acc[c]);
        }
    }

    const float* xb = x + ((long)b * SS + wave * 1024) * DD + lane;
    const int* labw = lab + wave * 1024;
    for (int r = 0; r < 1024; r += 8) {
        float v[8]; int l[8];
        #pragma unroll
        for (int u = 0; u < 8; ++u) { v[u] = xb[(r + u) * DD]; l[u] = labw[r + u]; }
        #pragma unroll
        for (int u = 0; u < 8; ++u) atomicAdd(&ssum[l[u] * DD + lane], v[u]);
    }
    __syncthreads();

    const int c = tid >> 6;
    const bool act = (tid < NC * DD);
    float slot = 0.f;
    if (act) slot = ssum[c * DD + lane] / (float)scnt[c];

    const float* Ws[2][3] = {{wm1, wm2, wm3}, {wv1, wv2, wv3}};
    const float* Bs[2][3] = {{bm1, bm2, bm3}, {bv1, bv2, bv3}};

    #pragma unroll
    for (int head = 0; head < 2; ++head) {
        if (act) hs[c][lane] = slot;
        float val = 0.f;
        #pragma unroll
        for (int layer = 0; layer < 3; ++layer) {
            const float* W = Ws[head][layer];
            for (int i = tid; i < DD * DD; i += 1024)
                w_lds[(i >> 6) * (DD + 1) + (i & 63)] = W[i];
            __syncthreads();
            if (act) {
                float z = Bs[head][layer][lane];
                #pragma unroll
                for (int d = 0; d < DD; ++d)
                    z += hs[c][d] * w_lds[lane * (DD + 1) + d];
                val = (layer < 2) ? fmaxf(z, 0.f)
                                  : (2.f / (1.f + __expf(-z)) - 1.f);
            }
            __syncthreads();
            if (act) hs[c][lane] = val;
        }
        if (act) out[head * (BB * NC * DD) + (b * NC + c) * DD + lane] = val;
        __syncthreads();
    }
}

__global__ __launch_bounds__(128) void init_fallback_kernel(
    const float* __restrict__ outro, const int* __restrict__ Kptr,
    float* __restrict__ out)
{
    const int t = threadIdx.x;
    const int head = t >> 6, lane = t & 63;
    const float* src = outro + head * (BB * NC * DD) + lane;
    float s = 0.f;
    for (int r = 0; r < BB * NC; ++r) s += src[r * DD];
    out[OUT_MAIN + t] = s / (float)(BB * Kptr[0]);
}

extern "C" void kernel_launch(void* const* d_in, const int* in_sizes, int n_in,
                              void* d_out, int out_size, void* d_ws, size_t ws_size,
                              hipStream_t stream)
{
    const float* x      = (const float*)d_in[0];
    const int*   labels = (const int*)d_in[1];
    const int*   K      = (const int*)d_in[2];
    const float* wm1 = (const float*)d_in[3];
    const float* bm1 = (const float*)d_in[4];
    const float* wm2 = (const float*)d_in[5];
    const float* bm2 = (const float*)d_in[6];
    const float* wm3 = (const float*)d_in[7];
    const float* bm3 = (const float*)d_in[8];
    const float* wv1 = (const float*)d_in[9];
    const float* bv1 = (const float*)d_in[10];
    const float* wv2 = (const float*)d_in[11];
    const float* bv2 = (const float*)d_in[12];
    const float* wv3 = (const float*)d_in[13];
    const float* bv3 = (const float*)d_in[14];
    float* out = (float*)d_out;

    if (ws_size >= (size_t)WS_WORDS * 4) {
        float* seg = (float*)d_ws;
        int*   cnt = (int*)((char*)d_ws + (size_t)BB * NC * DD * 4);
        zero_kernel<<<(WS_WORDS + 255) / 256, 256, 0, stream>>>(
            (int*)d_ws, WS_WORDS, out + OUT_MAIN);
        seg_kernel<<<NBLK, 256, 0, stream>>>(
            (const float4*)x, labels, seg, cnt);
        mlp_kernel<<<2 * BB, 1024, 0, stream>>>(
            seg, cnt,
            wm1, bm1, wm2, bm2, wm3, bm3,
            wv1, bv1, wv2, bv2, wv3, bv3, K, out);
    } else {
        fused_fallback_kernel<<<BB, 1024, 0, stream>>>(
            x, labels,
            wm1, bm1, wm2, bm2, wm3, bm3,
            wv1, bv1, wv2, bv2, wv3, bv3, out);
        init_fallback_kernel<<<1, 128, 0, stream>>>((const float*)d_out, K, out);
    }
}

// Round 7
// 227.113 us; speedup vs baseline: 1.8200x; 1.5220x over previous
//
#include <hip/hip_runtime.h>
#include <hip/hip_bf16.h>

#define NC 10
#define DD 64
#define BB 32
#define SS 16384
#define CHUNK 512
#define NCHUNK (SS / CHUNK)                  // 32
#define NBLK (BB * NCHUNK)                   // 1024
#define TSTR 65                              // merge-tile row stride (pad)
#define TSZ (NC * TSTR)                      // 650
#define OUT_MAIN (2 * BB * NC * DD)          // 40960
#define WS_WORDS (BB * NC * DD + BB * NC)    // 20800 words = 83,200 B

// -------------------------------------------- kernel 0: zero ws + init out --
__global__ __launch_bounds__(256) void zero_kernel(
    int* __restrict__ ws, int nws, float* __restrict__ out_init)
{
    int i = blockIdx.x * 256 + threadIdx.x;
    if (i < nws) ws[i] = 0;
    if (blockIdx.x == 0 && threadIdx.x < 2 * DD) out_init[threadIdx.x] = 0.f;
}

// ------------------------------------------------- kernel 1: segment sums ---
// 1024 blocks x 256 thr (4 waves, 4 blocks/CU, 16 waves/CU). Lane = dim; the
// row's label is WAVE-UNIFORM -> v_readlane into SGPR, accumulate into 10
// REGISTER accumulators via branchless fmac with scalar 0/1 mask.
// ZERO LDS atomics in the hot loop (rounds 3/4/6 showed ds_add_f32 retires
// ~3.2 cy/lane-RMW = the 174 us wall). Merge: plain ds_write -> block reduce
// -> global f32 atomics (655K lane-ops, not a wall at round-4 scale).
__global__ __launch_bounds__(256, 4) void seg_kernel(
    const float* __restrict__ x, const int* __restrict__ labels,
    float* __restrict__ seg, int* __restrict__ cnt)
{
    __shared__ float tiles[4][TSZ];            // 10,400 B
    __shared__ int scnt[NC];

    const int tid = threadIdx.x;
    const int blk = blockIdx.x;
    const int b = blk >> 5, chunk = blk & 31;
    const long row0 = (long)b * SS + chunk * CHUNK;
    const int w = tid >> 6, lane = tid & 63;

    if (tid < NC) scnt[tid] = 0;

    // wave w owns rows [w*128, (w+1)*128); lane holds labels 2*lane, 2*lane+1
    const int2 lv = ((const int2*)(labels + row0))[w * 64 + lane];
    const float* xr = x + (row0 + w * 128) * DD + lane;

    float acc[NC];
    #pragma unroll
    for (int c = 0; c < NC; ++c) acc[c] = 0.f;

    for (int r1 = 0; r1 < 128; r1 += 8) {
        float v[8];
        #pragma unroll
        for (int u = 0; u < 8; ++u)            // 8 x 256B coalesced in flight
            v[u] = xr[(r1 + u) * DD];
        #pragma unroll
        for (int u = 0; u < 8; ++u) {
            // row r1+u label: component u&1 (const), source lane (r1+u)/2
            const int l = __builtin_amdgcn_readlane(
                (u & 1) ? lv.y : lv.x, (r1 >> 1) + (u >> 1));  // SGPR
            #pragma unroll
            for (int c = 0; c < NC; ++c)       // s_cmp+s_cselect+v_fmac
                acc[c] = fmaf(v[u], (l == c) ? 1.f : 0.f, acc[c]);
        }
    }

    __syncthreads();                           // scnt zeroed & visible

    // counts: 2 ballots per cluster over the wave's 128 labels
    #pragma unroll
    for (int c = 0; c < NC; ++c) {
        int n = (int)__popcll(__ballot(lv.x == c))
              + (int)__popcll(__ballot(lv.y == c));
        if (lane == 0) atomicAdd(&scnt[c], n); // 40 lane-ops/block total
    }

    // register accs -> wave-private LDS tile (plain ds_write, 2-way banks)
    #pragma unroll
    for (int c = 0; c < NC; ++c) tiles[w][c * TSTR + lane] = acc[c];
    __syncthreads();

    for (int i = tid; i < NC * DD; i += 256) { // merge 4 waves -> global
        const int c = i >> 6, d = i & 63;
        float s = tiles[0][c * TSTR + d] + tiles[1][c * TSTR + d]
                + tiles[2][c * TSTR + d] + tiles[3][c * TSTR + d];
        unsafeAtomicAdd(&seg[b * (NC * DD) + i], s);
    }
    if (tid < NC) atomicAdd(&cnt[b * NC + tid], scnt[tid]);
}

// --------------------------------------------------- kernel 2: MLP heads ----
// 64 blocks (b x head) x 1024 thr; one float4 weight stage per thread/layer;
// waves 0..9 = cluster rows; init sums LDS-reduced, 1 global atomic per blk.
__global__ __launch_bounds__(1024) void mlp_kernel(
    const float* __restrict__ seg, const int* __restrict__ cnt,
    const float* wm1, const float* bm1, const float* wm2, const float* bm2,
    const float* wm3, const float* bm3,
    const float* wv1, const float* bv1, const float* wv2, const float* bv2,
    const float* wv3, const float* bv3,
    const int* __restrict__ Kptr, float* __restrict__ out)
{
    const int blk = blockIdx.x;                // b*2 + head
    const int b = blk >> 1, head = blk & 1;
    const int tid = threadIdx.x;
    const int w = tid >> 6, lane = tid & 63;

    __shared__ float w_lds[DD * TSTR];         // 16,640 B
    __shared__ float hs[NC][DD];
    __shared__ float hsum[DD];

    const float* Wl[3] = {head ? wv1 : wm1, head ? wv2 : wm2, head ? wv3 : wm3};
    const float* Bl[3] = {head ? bv1 : bm1, head ? bv2 : bm2, head ? bv3 : bm3};

    if (tid < DD) hsum[tid] = 0.f;
    if (w < NC) hs[w][lane] = seg[(b * NC + w) * DD + lane]
                              / (float)cnt[b * NC + w];
    float val = 0.f;
    const int j = tid >> 4, d0 = (tid & 15) * 4;   // stage target

    #pragma unroll
    for (int layer = 0; layer < 3; ++layer) {
        const float4 wv = ((const float4*)Wl[layer])[tid];  // 1 insn / thread
        const float bias = (w < NC) ? Bl[layer][lane] : 0.f;
        __syncthreads();                       // prev-layer dots done
        w_lds[j * TSTR + d0 + 0] = wv.x;
        w_lds[j * TSTR + d0 + 1] = wv.y;
        w_lds[j * TSTR + d0 + 2] = wv.z;
        w_lds[j * TSTR + d0 + 3] = wv.w;
        __syncthreads();                       // W staged
        if (w < NC) {
            float z = bias;
            #pragma unroll
            for (int d = 0; d < DD; ++d)
                z += hs[w][d] * w_lds[lane * TSTR + d];
            val = (layer < 2) ? fmaxf(z, 0.f)
                              : (2.f / (1.f + __expf(-z)) - 1.f);
            hs[w][lane] = val;                 // barrier-ordered vs next read
        }
    }
    if (w < NC) {
        out[head * (BB * NC * DD) + (b * NC + w) * DD + lane] = val;
        atomicAdd(&hsum[lane], val);
    }
    __syncthreads();
    if (tid < DD)
        unsafeAtomicAdd(&out[OUT_MAIN + head * DD + tid],
                        hsum[tid] / (float)(BB * Kptr[0]));
}

// ------------------------------------- fallback: fused, zero-ws, 32 blocks --
__global__ __launch_bounds__(1024) void fused_fallback_kernel(
    const float* __restrict__ x, const int* __restrict__ labels,
    const float* wm1, const float* bm1, const float* wm2, const float* bm2,
    const float* wm3, const float* bm3,
    const float* wv1, const float* bv1, const float* wv2, const float* bv2,
    const float* wv3, const float* bv3,
    float* __restrict__ out)
{
    __shared__ float ssum[NC * DD];
    __shared__ int scnt[NC];
    __shared__ float hs[NC][DD];
    __shared__ float w_lds[DD * (DD + 1)];

    const int tid = threadIdx.x;
    const int b = blockIdx.x;
    const int wave = tid >> 6, lane = tid & 63;

    for (int i = tid; i < NC * DD; i += 1024) ssum[i] = 0.f;
    if (tid < NC) scnt[tid] = 0;
    __syncthreads();

    const int* lab = labels + b * SS;
    {
        int c_acc[NC];
        #pragma unroll
        for (int c = 0; c < NC; ++c) c_acc[c] = 0;
        for (int i = 0; i < 16; ++i) {
            int l = lab[wave * 1024 + i * 64 + lane];
            #pragma unroll
            for (int c = 0; c < NC; ++c)
                c_acc[c] += (int)__popcll(__ballot(l == c));
        }
        if (lane == 0) {
            #pragma unroll
            for (int c = 0; c < NC; ++c) atomicAdd(&scnt[c], c_acc[c]);
        }
    }

    const float* xb = x + ((long)b * SS + wave * 1024) * DD + lane;
    const int* labw = lab + wave * 1024;
    for (int r = 0; r < 1024; r += 8) {
        float v[8]; int l[8];
        #pragma unroll
        for (int u = 0; u < 8; ++u) { v[u] = xb[(r + u) * DD]; l[u] = labw[r + u]; }
        #pragma unroll
        for (int u = 0; u < 8; ++u) atomicAdd(&ssum[l[u] * DD + lane], v[u]);
    }
    __syncthreads();

    const int c = tid >> 6;
    const bool act = (tid < NC * DD);
    float slot = 0.f;
    if (act) slot = ssum[c * DD + lane] / (float)scnt[c];

    const float* Ws[2][3] = {{wm1, wm2, wm3}, {wv1, wv2, wv3}};
    const float* Bs[2][3] = {{bm1, bm2, bm3}, {bv1, bv2, bv3}};

    #pragma unroll
    for (int head = 0; head < 2; ++head) {
        if (act) hs[c][lane] = slot;
        float val = 0.f;
        #pragma unroll
        for (int layer = 0; layer < 3; ++layer) {
            const float* W = Ws[head][layer];
            for (int i = tid; i < DD * DD; i += 1024)
                w_lds[(i >> 6) * (DD + 1) + (i & 63)] = W[i];
            __syncthreads();
            if (act) {
                float z = Bs[head][layer][lane];
                #pragma unroll
                for (int d = 0; d < DD; ++d)
                    z += hs[c][d] * w_lds[lane * (DD + 1) + d];
                val = (layer < 2) ? fmaxf(z, 0.f)
                                  : (2.f / (1.f + __expf(-z)) - 1.f);
            }
            __syncthreads();
            if (act) hs[c][lane] = val;
        }
        if (act) out[head * (BB * NC * DD) + (b * NC + c) * DD + lane] = val;
        __syncthreads();
    }
}

__global__ __launch_bounds__(128) void init_fallback_kernel(
    const float* __restrict__ outro, const int* __restrict__ Kptr,
    float* __restrict__ out)
{
    const int t = threadIdx.x;
    const int head = t >> 6, lane = t & 63;
    const float* src = outro + head * (BB * NC * DD) + lane;
    float s = 0.f;
    for (int r = 0; r < BB * NC; ++r) s += src[r * DD];
    out[OUT_MAIN + t] = s / (float)(BB * Kptr[0]);
}

extern "C" void kernel_launch(void* const* d_in, const int* in_sizes, int n_in,
                              void* d_out, int out_size, void* d_ws, size_t ws_size,
                              hipStream_t stream)
{
    const float* x      = (const float*)d_in[0];
    const int*   labels = (const int*)d_in[1];
    const int*   K      = (const int*)d_in[2];
    const float* wm1 = (const float*)d_in[3];
    const float* bm1 = (const float*)d_in[4];
    const float* wm2 = (const float*)d_in[5];
    const float* bm2 = (const float*)d_in[6];
    const float* wm3 = (const float*)d_in[7];
    const float* bm3 = (const float*)d_in[8];
    const float* wv1 = (const float*)d_in[9];
    const float* bv1 = (const float*)d_in[10];
    const float* wv2 = (const float*)d_in[11];
    const float* bv2 = (const float*)d_in[12];
    const float* wv3 = (const float*)d_in[13];
    const float* bv3 = (const float*)d_in[14];
    float* out = (float*)d_out;

    if (ws_size >= (size_t)WS_WORDS * 4) {
        float* seg = (float*)d_ws;
        int*   cnt = (int*)((char*)d_ws + (size_t)BB * NC * DD * 4);
        zero_kernel<<<(WS_WORDS + 255) / 256, 256, 0, stream>>>(
            (int*)d_ws, WS_WORDS, out + OUT_MAIN);
        seg_kernel<<<NBLK, 256, 0, stream>>>(x, labels, seg, cnt);
        mlp_kernel<<<2 * BB, 1024, 0, stream>>>(
            seg, cnt,
            wm1, bm1, wm2, bm2, wm3, bm3,
            wv1, bv1, wv2, bv2, wv3, bv3, K, out);
    } else {
        fused_fallback_kernel<<<BB, 1024, 0, stream>>>(
            x, labels,
            wm1, bm1, wm2, bm2, wm3, bm3,
            wv1, bv1, wv2, bv2, wv3, bv3, out);
        init_fallback_kernel<<<1, 128, 0, stream>>>((const float*)d_out, K, out);
    }
}